// Round 1
// baseline (59.845 us; speedup 1.0000x reference)
//
#include <hip/hip_runtime.h>
#include <math.h>

#define BLOCK 256
#define GRID  2048
#define NPART 2048

// Online-softmax pair combine: (m, z) <- merge of (m, z) and (m2, z2).
// Init state m=-1e30, z=0 is safe: exp(-1e30 - anything_finite) underflows to 0,
// and (-1e30) - (-1e30) = 0 (no inf-inf NaN).
__device__ __forceinline__ void combine(float& m, float& z, float m2, float z2) {
    float nm = fmaxf(m, m2);
    z = z * __expf(m - nm) + z2 * __expf(m2 - nm);
    m = nm;
}

// Pass 1: per-block online (max, sum-exp) partials over predictions.
__global__ __launch_bounds__(BLOCK) void k_pass1(const float* __restrict__ x, long long n,
                                                 float* __restrict__ part_m,
                                                 float* __restrict__ part_z) {
    long long n4 = n >> 2;
    long long tid = (long long)blockIdx.x * BLOCK + threadIdx.x;
    long long stride = (long long)gridDim.x * BLOCK;
    float m = -1e30f, z = 0.f;
    const float4* x4 = (const float4*)x;
    for (long long i = tid; i < n4; i += stride) {
        float4 v = x4[i];
        float mv = fmaxf(fmaxf(v.x, v.y), fmaxf(v.z, v.w));
        float nm = fmaxf(m, mv);
        z = z * __expf(m - nm)
          + __expf(v.x - nm) + __expf(v.y - nm)
          + __expf(v.z - nm) + __expf(v.w - nm);
        m = nm;
    }
    // scalar tail (n % 4) — no-op for N=16M but kept for safety
    if (blockIdx.x == 0 && threadIdx.x == 0) {
        for (long long i = (n4 << 2); i < n; ++i) {
            float v = x[i];
            float nm = fmaxf(m, v);
            z = z * __expf(m - nm) + __expf(v - nm);
            m = nm;
        }
    }
    // wave (64-lane) butterfly reduce
    #pragma unroll
    for (int off = 32; off > 0; off >>= 1) {
        float m2 = __shfl_xor(m, off);
        float z2 = __shfl_xor(z, off);
        combine(m, z, m2, z2);
    }
    __shared__ float sm[BLOCK / 64], sz[BLOCK / 64];
    int wave = threadIdx.x >> 6;
    int lane = threadIdx.x & 63;
    if (lane == 0) { sm[wave] = m; sz[wave] = z; }
    __syncthreads();
    if (threadIdx.x == 0) {
        #pragma unroll
        for (int w = 1; w < BLOCK / 64; ++w) combine(m, z, sm[w], sz[w]);
        part_m[blockIdx.x] = m;
        part_z[blockIdx.x] = z;
    }
}

// Pass 1b: single-wave combine of the NPART partials -> (m, Z).
__global__ __launch_bounds__(64) void k_reduce1(const float* __restrict__ part_m,
                                                const float* __restrict__ part_z,
                                                int nb, float* __restrict__ mz) {
    float m = -1e30f, z = 0.f;
    for (int i = threadIdx.x; i < nb; i += 64) combine(m, z, part_m[i], part_z[i]);
    #pragma unroll
    for (int off = 32; off > 0; off >>= 1) {
        float m2 = __shfl_xor(m, off);
        float z2 = __shfl_xor(z, off);
        combine(m, z, m2, z2);
    }
    if (threadIdx.x == 0) { mz[0] = m; mz[1] = z; }
}

// Pass 2: s_i = exp(x_i - m)/Z; accumulate T = sum exp(s_i), dot = sum gt_i*s_i,
// gsum = sum gt_i. Per-block float partials.
__global__ __launch_bounds__(BLOCK) void k_pass2(const float* __restrict__ x,
                                                 const float* __restrict__ g,
                                                 long long n,
                                                 const float* __restrict__ mz,
                                                 float* __restrict__ pt,
                                                 float* __restrict__ pd,
                                                 float* __restrict__ pg) {
    float m = mz[0];
    float invZ = 1.0f / mz[1];
    long long n4 = n >> 2;
    long long tid = (long long)blockIdx.x * BLOCK + threadIdx.x;
    long long stride = (long long)gridDim.x * BLOCK;
    float t = 0.f, dot = 0.f, gs = 0.f;
    const float4* x4 = (const float4*)x;
    const float4* g4 = (const float4*)g;
    for (long long i = tid; i < n4; i += stride) {
        float4 v = x4[i];
        float4 w = g4[i];
        float s0 = __expf(v.x - m) * invZ;
        float s1 = __expf(v.y - m) * invZ;
        float s2 = __expf(v.z - m) * invZ;
        float s3 = __expf(v.w - m) * invZ;
        t   += __expf(s0) + __expf(s1) + __expf(s2) + __expf(s3);
        dot += w.x * s0 + w.y * s1 + w.z * s2 + w.w * s3;
        gs  += w.x + w.y + w.z + w.w;
    }
    if (blockIdx.x == 0 && threadIdx.x == 0) {
        for (long long i = (n4 << 2); i < n; ++i) {
            float s = __expf(x[i] - m) * invZ;
            t += __expf(s);
            dot += g[i] * s;
            gs += g[i];
        }
    }
    #pragma unroll
    for (int off = 32; off > 0; off >>= 1) {
        t   += __shfl_xor(t, off);
        dot += __shfl_xor(dot, off);
        gs  += __shfl_xor(gs, off);
    }
    __shared__ float st[BLOCK / 64], sd[BLOCK / 64], sg[BLOCK / 64];
    int wave = threadIdx.x >> 6;
    int lane = threadIdx.x & 63;
    if (lane == 0) { st[wave] = t; sd[wave] = dot; sg[wave] = gs; }
    __syncthreads();
    if (threadIdx.x == 0) {
        #pragma unroll
        for (int w = 1; w < BLOCK / 64; ++w) { t += st[w]; dot += sd[w]; gs += sg[w]; }
        pt[blockIdx.x] = t;
        pd[blockIdx.x] = dot;
        pg[blockIdx.x] = gs;
    }
}

// Final: double-precision combine of partials; loss = log(T)*gsum - dot.
__global__ __launch_bounds__(64) void k_final(const float* __restrict__ pt,
                                              const float* __restrict__ pd,
                                              const float* __restrict__ pg,
                                              int nb, float* __restrict__ out) {
    double t = 0.0, d = 0.0, gs = 0.0;
    for (int i = threadIdx.x; i < nb; i += 64) {
        t += (double)pt[i];
        d += (double)pd[i];
        gs += (double)pg[i];
    }
    #pragma unroll
    for (int off = 32; off > 0; off >>= 1) {
        t  += __shfl_xor(t, off);
        d  += __shfl_xor(d, off);
        gs += __shfl_xor(gs, off);
    }
    if (threadIdx.x == 0) {
        out[0] = (float)(log(t) * gs - d);
    }
}

extern "C" void kernel_launch(void* const* d_in, const int* in_sizes, int n_in,
                              void* d_out, int out_size, void* d_ws, size_t ws_size,
                              hipStream_t stream) {
    const float* x = (const float*)d_in[0];       // predictions [1, N]
    const float* g = (const float*)d_in[1];       // ground_truth_probs [1, N]
    long long n = (long long)in_sizes[0];
    float* ws = (float*)d_ws;
    float* part_m = ws;                 // [NPART]
    float* part_z = ws + NPART;         // [NPART]
    float* mz     = ws + 2 * NPART;     // [2]
    float* pt     = ws + 2 * NPART + 64;// [NPART]
    float* pd     = pt + NPART;         // [NPART]
    float* pg     = pd + NPART;         // [NPART]

    k_pass1<<<GRID, BLOCK, 0, stream>>>(x, n, part_m, part_z);
    k_reduce1<<<1, 64, 0, stream>>>(part_m, part_z, NPART, mz);
    k_pass2<<<GRID, BLOCK, 0, stream>>>(x, g, n, mz, pt, pd, pg);
    k_final<<<1, 64, 0, stream>>>(pt, pd, pg, NPART, (float*)d_out);
}